// Round 1
// baseline (304.087 us; speedup 1.0000x reference)
//
#include <hip/hip_runtime.h>

// ---------------------------------------------------------------------------
// AGNN: h = relu(x@W1^T+b1); 4x [ h = relu(agnn(h)) ]; out = h@W2^T+b2
// N=100000, E=1600000, IN=128, HID=OUT=64, float32 in/out.
// Between layers: xn = h/(||h||+eps) stored FP16 (128 B/row) + nrm f32.
//   p = exp2( dot(xn_i * log2e, xn_j) );  out_i = sum p * nrm_j * xn_j / sum p
// agnn: nodes processed in SEGMENT-LOCAL degree-sorted order (perm).
// This round:
//   - rowptr via O(E) boundary scan (no binary search chains)
//   - perm: SEG=1024, 1024 thr, 98 blocks, 256-bucket LDS counting sort
//   - gemm1/gemm2: 8x4 register tile (128-node x 64-out block tile) ->
//     0.75 B/FLOP LDS traffic, FMA-bound instead of LDS-bound.
// agnn kernel unchanged from the 299 us version.
// ---------------------------------------------------------------------------

typedef _Float16 h2 __attribute__((ext_vector_type(2)));

union U4H { uint4 u; h2 h[4]; };
union U2H { uint2 u; h2 h[2]; };
union UHI { unsigned u; h2 h; };

#define DEV_INLINE __device__ __forceinline__

DEV_INLINE h2 mkh2(float a, float b) {
    h2 r; r.x = (_Float16)a; r.y = (_Float16)b; return r;
}

// ptr[i] = lower_bound(row, i). Thread e covers i in (row[e-1], row[e]].
__global__ __launch_bounds__(256) void build_rowptr_scan(const int* __restrict__ row,
                                                         int* __restrict__ ptr,
                                                         int N, int E) {
    int e = blockIdx.x * blockDim.x + threadIdx.x;
    if (e >= E) return;
    const int r1 = row[e];
    const int r0 = (e == 0) ? -1 : row[e - 1];
    for (int i = r0 + 1; i <= r1; ++i) ptr[i] = e;
    if (e == E - 1) {
        for (int i = r1 + 1; i <= N; ++i) ptr[i] = E;
    }
}

// Segment-local counting sort by degree. One 1024-thread block per 1024-node
// segment (1 node per thread); 256-bucket LDS histogram + 8-step scan.
#define PSEG 1024
__global__ __launch_bounds__(1024) void build_perm_seg(const int* __restrict__ ptr,
                                                       int* __restrict__ perm,
                                                       int N) {
    __shared__ int hist[256];
    __shared__ int tmp[256];
    const int t    = threadIdx.x;
    const int base = blockIdx.x * PSEG;
    const int end  = (base + PSEG < N) ? base + PSEG : N;
    const int cnt  = end - base;

    if (t < 256) hist[t] = 0;
    __syncthreads();

    int d = -1;
    if (t < cnt) {
        d = ptr[base + t + 1] - ptr[base + t];
        if (d > 255) d = 255;
        atomicAdd(&hist[d], 1);
    }
    __syncthreads();

    int h0 = (t < 256) ? hist[t] : 0;
    // Hillis-Steele inclusive scan over 256 buckets, ping-pong (8 iters)
    int* src = hist; int* dst = tmp;
    for (int off = 1; off < 256; off <<= 1) {
        if (t < 256) dst[t] = src[t] + (t >= off ? src[t - off] : 0);
        __syncthreads();
        int* tt = src; src = dst; dst = tt;
    }
    // 8 iterations -> src == hist. Convert to exclusive offsets.
    if (t < 256) src[t] -= h0;
    __syncthreads();

    if (t < cnt) {
        int pos = base + atomicAdd(&src[d], 1);
        perm[pos] = base + t;
    }
}

// r = relu(x[i,:128]@W1^T + b1); xn[i]=f16(r/(||r||+eps)); nrm[i]=||r||+eps
// Tile: 128 nodes x 64 outs, 256 threads, thread = 8 nodes x 4 outs.
__global__ __launch_bounds__(256) void gemm1_relu(const float* __restrict__ x,
                                                  const float* __restrict__ W1,
                                                  const float* __restrict__ b1,
                                                  unsigned short* __restrict__ xn,
                                                  float* __restrict__ nrm,
                                                  int N) {
    __shared__ __align__(16) float Wt[32 * 64];    // Wt[k*64+o], k in chunk
    __shared__ __align__(16) float xT[32 * 128];   // xT[k*128+m]
    const int tid  = threadIdx.x;
    const int tx   = tid & 15;    // 4 outs at 4*tx
    const int ty   = tid >> 4;    // 8 nodes at 8*ty
    const int base = blockIdx.x * 128;

    float4 b4 = ((const float4*)b1)[tx];
    float4 acc[8];
#pragma unroll
    for (int mm = 0; mm < 8; ++mm) acc[mm] = b4;

    for (int kc = 0; kc < 128; kc += 32) {
        if (kc) __syncthreads();
        const float4* W4 = (const float4*)W1;
#pragma unroll
        for (int it = 0; it < 2; ++it) {
            int idx = tid + it * 256;             // 512 total
            int o = idx & 63, k4 = idx >> 6;      // k4 in [0,8)
            float4 v = W4[o * 32 + (kc >> 2) + k4];
            Wt[(4 * k4 + 0) * 64 + o] = v.x;
            Wt[(4 * k4 + 1) * 64 + o] = v.y;
            Wt[(4 * k4 + 2) * 64 + o] = v.z;
            Wt[(4 * k4 + 3) * 64 + o] = v.w;
        }
        const float4* x4p = (const float4*)x;
#pragma unroll
        for (int it = 0; it < 4; ++it) {
            int idx = tid + it * 256;             // 1024 total
            int mm = idx & 127, k4 = idx >> 7;    // k4 in [0,8)
            int node = base + mm;
            float4 v = make_float4(0.f, 0.f, 0.f, 0.f);
            if (node < N) v = x4p[(size_t)node * 32 + (kc >> 2) + k4];
            xT[(4 * k4 + 0) * 128 + mm] = v.x;
            xT[(4 * k4 + 1) * 128 + mm] = v.y;
            xT[(4 * k4 + 2) * 128 + mm] = v.z;
            xT[(4 * k4 + 3) * 128 + mm] = v.w;
        }
        __syncthreads();

#pragma unroll 4
        for (int k = 0; k < 32; ++k) {
            const float4 w4  = *(const float4*)&Wt[k * 64 + 4 * tx];
            const float4 xa  = *(const float4*)&xT[k * 128 + 8 * ty];
            const float4 xb  = *(const float4*)&xT[k * 128 + 8 * ty + 4];
            acc[0].x = fmaf(xa.x, w4.x, acc[0].x);
            acc[0].y = fmaf(xa.x, w4.y, acc[0].y);
            acc[0].z = fmaf(xa.x, w4.z, acc[0].z);
            acc[0].w = fmaf(xa.x, w4.w, acc[0].w);
            acc[1].x = fmaf(xa.y, w4.x, acc[1].x);
            acc[1].y = fmaf(xa.y, w4.y, acc[1].y);
            acc[1].z = fmaf(xa.y, w4.z, acc[1].z);
            acc[1].w = fmaf(xa.y, w4.w, acc[1].w);
            acc[2].x = fmaf(xa.z, w4.x, acc[2].x);
            acc[2].y = fmaf(xa.z, w4.y, acc[2].y);
            acc[2].z = fmaf(xa.z, w4.z, acc[2].z);
            acc[2].w = fmaf(xa.z, w4.w, acc[2].w);
            acc[3].x = fmaf(xa.w, w4.x, acc[3].x);
            acc[3].y = fmaf(xa.w, w4.y, acc[3].y);
            acc[3].z = fmaf(xa.w, w4.z, acc[3].z);
            acc[3].w = fmaf(xa.w, w4.w, acc[3].w);
            acc[4].x = fmaf(xb.x, w4.x, acc[4].x);
            acc[4].y = fmaf(xb.x, w4.y, acc[4].y);
            acc[4].z = fmaf(xb.x, w4.z, acc[4].z);
            acc[4].w = fmaf(xb.x, w4.w, acc[4].w);
            acc[5].x = fmaf(xb.y, w4.x, acc[5].x);
            acc[5].y = fmaf(xb.y, w4.y, acc[5].y);
            acc[5].z = fmaf(xb.y, w4.z, acc[5].z);
            acc[5].w = fmaf(xb.y, w4.w, acc[5].w);
            acc[6].x = fmaf(xb.z, w4.x, acc[6].x);
            acc[6].y = fmaf(xb.z, w4.y, acc[6].y);
            acc[6].z = fmaf(xb.z, w4.z, acc[6].z);
            acc[6].w = fmaf(xb.z, w4.w, acc[6].w);
            acc[7].x = fmaf(xb.w, w4.x, acc[7].x);
            acc[7].y = fmaf(xb.w, w4.y, acc[7].y);
            acc[7].z = fmaf(xb.w, w4.z, acc[7].z);
            acc[7].w = fmaf(xb.w, w4.w, acc[7].w);
        }
    }

#pragma unroll
    for (int mm = 0; mm < 8; ++mm) {
        float4 r = acc[mm];
        r.x = fmaxf(r.x, 0.f); r.y = fmaxf(r.y, 0.f);
        r.z = fmaxf(r.z, 0.f); r.w = fmaxf(r.w, 0.f);
        float s = fmaf(r.x, r.x, fmaf(r.y, r.y, fmaf(r.z, r.z, r.w * r.w)));
        s += __shfl_xor(s, 1, 64);
        s += __shfl_xor(s, 2, 64);
        s += __shfl_xor(s, 4, 64);
        s += __shfl_xor(s, 8, 64);
        const float nn  = sqrtf(s) + 1e-12f;
        const float inv = 1.f / nn;
        int node = base + 8 * ty + mm;
        if (node < N) {
            U2H pk;
            pk.h[0] = mkh2(r.x * inv, r.y * inv);
            pk.h[1] = mkh2(r.z * inv, r.w * inv);
            *(uint2*)&xn[(size_t)node * 64 + 4 * tx] = pk.u;
            if (tx == mm) nrm[node] = nn;
        }
    }
}

// 4 nodes per wave (16 lanes each, degree-sorted); 2 edge-groups x 8 lanes;
// 2 edges in flight per group.  (UNCHANGED from 299 us version.)
__global__ __launch_bounds__(256) void agnn_layer(const uint4* __restrict__ xn4,
                                                  const float* __restrict__ nrm,
                                                  const int* __restrict__ ptr,
                                                  const int* __restrict__ col,
                                                  const int* __restrict__ perm,
                                                  uint4* __restrict__ xo4,
                                                  float* __restrict__ nrmo,
                                                  int N) {
    const int tid  = threadIdx.x;
    const int lane = tid & 63;
    const int g    = (lane >> 3) & 1;   // edge group 0..1 within 16-lane quarter
    const int sub  = lane & 7;          // 16B chunk of the 128B row
    const int slot = blockIdx.x * 16 + (tid >> 4);
    if (slot >= N) return;
    const int i = perm[slot];

    U4H hi_;
    hi_.u = xn4[(unsigned)i * 8u + sub];
    {
        const _Float16 L2E = (_Float16)1.4426950408889634f;
        h2 l2 = {L2E, L2E};
#pragma unroll
        for (int t = 0; t < 4; ++t) hi_.h[t] *= l2;   // p = exp2(dot)
    }

    const int p0 = ptr[i], p1 = ptr[i + 1];

    float den = 0.f;
    U4H acc;
    acc.h[0] = mkh2(0.f, 0.f); acc.h[1] = mkh2(0.f, 0.f);
    acc.h[2] = mkh2(0.f, 0.f); acc.h[3] = mkh2(0.f, 0.f);

#define EDGE_BODY(VU, NRMJ)                                                  \
    {                                                                        \
        U4H xa; xa.u = (VU);                                                 \
        float s = 0.f;                                                       \
        s = __builtin_amdgcn_fdot2(hi_.h[0], xa.h[0], s, false);             \
        s = __builtin_amdgcn_fdot2(hi_.h[1], xa.h[1], s, false);             \
        s = __builtin_amdgcn_fdot2(hi_.h[2], xa.h[2], s, false);             \
        s = __builtin_amdgcn_fdot2(hi_.h[3], xa.h[3], s, false);             \
        s += __shfl_xor(s, 1, 64);                                           \
        s += __shfl_xor(s, 2, 64);                                           \
        s += __shfl_xor(s, 4, 64);                                           \
        const float p = exp2f(s);                                            \
        den += p;                                                            \
        const _Float16 wh = (_Float16)(p * (NRMJ));                          \
        h2 w2 = {wh, wh};                                                    \
        acc.h[0] += w2 * xa.h[0];                                            \
        acc.h[1] += w2 * xa.h[1];                                            \
        acc.h[2] += w2 * xa.h[2];                                            \
        acc.h[3] += w2 * xa.h[3];                                            \
    }

    int e = p0 + g;
    for (; e + 2 < p1; e += 4) {          // 2 edges per group in flight
        const int ja = col[e];
        const int jb = col[e + 2];
        const uint4 va = xn4[(unsigned)ja * 8u + sub];
        const uint4 vb = xn4[(unsigned)jb * 8u + sub];
        const float na = nrm[ja];
        const float nb = nrm[jb];
        EDGE_BODY(va, na)
        EDGE_BODY(vb, nb)
    }
    if (e < p1) {
        const int j = col[e];
        const uint4 v = xn4[(unsigned)j * 8u + sub];
        const float nj = nrm[j];
        EDGE_BODY(v, nj)
    }
#undef EDGE_BODY

    // merge the 2 edge-groups (within the 16-lane quarter): xor 8
    {
        den += __shfl_xor(den, 8, 64);
#pragma unroll
        for (int t = 0; t < 4; ++t) {
            UHI a; a.h = acc.h[t];
            UHI b; b.u = (unsigned)__shfl_xor((int)a.u, 8, 64);
            acc.h[t] = a.h + b.h;
        }
    }

    const float id = 1.f / fmaxf(den, 1e-12f);
    float o[8];
#pragma unroll
    for (int t = 0; t < 4; ++t) {
        o[2 * t]     = fmaxf((float)acc.h[t].x * id, 0.f);
        o[2 * t + 1] = fmaxf((float)acc.h[t].y * id, 0.f);
    }

    float s2 = 0.f;
#pragma unroll
    for (int t = 0; t < 8; ++t) s2 = fmaf(o[t], o[t], s2);
    s2 += __shfl_xor(s2, 1, 64);
    s2 += __shfl_xor(s2, 2, 64);
    s2 += __shfl_xor(s2, 4, 64);
    const float nn  = sqrtf(s2) + 1e-12f;
    const float inv = 1.f / nn;

    if (g == 0) {
        U4H ov;
        ov.h[0] = mkh2(o[0] * inv, o[1] * inv);
        ov.h[1] = mkh2(o[2] * inv, o[3] * inv);
        ov.h[2] = mkh2(o[4] * inv, o[5] * inv);
        ov.h[3] = mkh2(o[6] * inv, o[7] * inv);
        xo4[(unsigned)i * 8u + sub] = ov.u;
        if (sub == 0) nrmo[i] = nn;
    }
}

// out[i,:64] = (xn[i]*nrm[i]) @ W2^T + b2   (f32 out)
// Tile: 128 nodes x 64 outs, 256 threads, thread = 8 nodes x 4 outs.
__global__ __launch_bounds__(256) void gemm2(const unsigned short* __restrict__ xn,
                                             const float* __restrict__ nrm,
                                             const float* __restrict__ W2,
                                             const float* __restrict__ b2,
                                             float* __restrict__ out,
                                             int N) {
    __shared__ __align__(16) float Wt[64 * 64];    // 16 KiB
    __shared__ __align__(16) float xT[64 * 128];   // 32 KiB
    const int tid  = threadIdx.x;
    const int tx   = tid & 15;
    const int ty   = tid >> 4;
    const int base = blockIdx.x * 128;

    {
        const float4* W4 = (const float4*)W2;
#pragma unroll
        for (int it = 0; it < 4; ++it) {
            int idx = tid + it * 256;              // 1024 total
            int o = idx & 63, k4 = idx >> 6;       // k4 in [0,16)
            float4 v = W4[o * 16 + k4];
            Wt[(4 * k4 + 0) * 64 + o] = v.x;
            Wt[(4 * k4 + 1) * 64 + o] = v.y;
            Wt[(4 * k4 + 2) * 64 + o] = v.z;
            Wt[(4 * k4 + 3) * 64 + o] = v.w;
        }
        const uint2* x2 = (const uint2*)xn;
#pragma unroll
        for (int it = 0; it < 8; ++it) {
            int idx = tid + it * 256;              // 2048 total
            int mm = idx & 127, k4 = idx >> 7;     // k4 in [0,16)
            int node = base + mm;
            U2H v; v.u = make_uint2(0u, 0u);
            float nn = 0.f;
            if (node < N) { v.u = x2[(size_t)node * 16 + k4]; nn = nrm[node]; }
            xT[(4 * k4 + 0) * 128 + mm] = (float)v.h[0].x * nn;
            xT[(4 * k4 + 1) * 128 + mm] = (float)v.h[0].y * nn;
            xT[(4 * k4 + 2) * 128 + mm] = (float)v.h[1].x * nn;
            xT[(4 * k4 + 3) * 128 + mm] = (float)v.h[1].y * nn;
        }
    }
    __syncthreads();

    float4 b4 = ((const float4*)b2)[tx];
    float4 acc[8];
#pragma unroll
    for (int mm = 0; mm < 8; ++mm) acc[mm] = b4;

#pragma unroll 4
    for (int k = 0; k < 64; ++k) {
        const float4 w4  = *(const float4*)&Wt[k * 64 + 4 * tx];
        const float4 xa  = *(const float4*)&xT[k * 128 + 8 * ty];
        const float4 xb  = *(const float4*)&xT[k * 128 + 8 * ty + 4];
        acc[0].x = fmaf(xa.x, w4.x, acc[0].x);
        acc[0].y = fmaf(xa.x, w4.y, acc[0].y);
        acc[0].z = fmaf(xa.x, w4.z, acc[0].z);
        acc[0].w = fmaf(xa.x, w4.w, acc[0].w);
        acc[1].x = fmaf(xa.y, w4.x, acc[1].x);
        acc[1].y = fmaf(xa.y, w4.y, acc[1].y);
        acc[1].z = fmaf(xa.y, w4.z, acc[1].z);
        acc[1].w = fmaf(xa.y, w4.w, acc[1].w);
        acc[2].x = fmaf(xa.z, w4.x, acc[2].x);
        acc[2].y = fmaf(xa.z, w4.y, acc[2].y);
        acc[2].z = fmaf(xa.z, w4.z, acc[2].z);
        acc[2].w = fmaf(xa.z, w4.w, acc[2].w);
        acc[3].x = fmaf(xa.w, w4.x, acc[3].x);
        acc[3].y = fmaf(xa.w, w4.y, acc[3].y);
        acc[3].z = fmaf(xa.w, w4.z, acc[3].z);
        acc[3].w = fmaf(xa.w, w4.w, acc[3].w);
        acc[4].x = fmaf(xb.x, w4.x, acc[4].x);
        acc[4].y = fmaf(xb.x, w4.y, acc[4].y);
        acc[4].z = fmaf(xb.x, w4.z, acc[4].z);
        acc[4].w = fmaf(xb.x, w4.w, acc[4].w);
        acc[5].x = fmaf(xb.y, w4.x, acc[5].x);
        acc[5].y = fmaf(xb.y, w4.y, acc[5].y);
        acc[5].z = fmaf(xb.y, w4.z, acc[5].z);
        acc[5].w = fmaf(xb.y, w4.w, acc[5].w);
        acc[6].x = fmaf(xb.z, w4.x, acc[6].x);
        acc[6].y = fmaf(xb.z, w4.y, acc[6].y);
        acc[6].z = fmaf(xb.z, w4.z, acc[6].z);
        acc[6].w = fmaf(xb.z, w4.w, acc[6].w);
        acc[7].x = fmaf(xb.w, w4.x, acc[7].x);
        acc[7].y = fmaf(xb.w, w4.y, acc[7].y);
        acc[7].z = fmaf(xb.w, w4.z, acc[7].z);
        acc[7].w = fmaf(xb.w, w4.w, acc[7].w);
    }

#pragma unroll
    for (int mm = 0; mm < 8; ++mm) {
        int node = base + 8 * ty + mm;
        if (node < N) *(float4*)&out[(size_t)node * 64 + 4 * tx] = acc[mm];
    }
}

extern "C" void kernel_launch(void* const* d_in, const int* in_sizes, int n_in,
                              void* d_out, int out_size, void* d_ws, size_t ws_size,
                              hipStream_t stream) {
    const float* x   = (const float*)d_in[0];
    const int*   row = (const int*)d_in[1];
    const int*   col = (const int*)d_in[2];
    const float* W1  = (const float*)d_in[3];
    const float* b1  = (const float*)d_in[4];
    const float* W2  = (const float*)d_in[5];
    const float* b2  = (const float*)d_in[6];
    float* out = (float*)d_out;

    const int N = in_sizes[0] / 128;
    const int E = in_sizes[1];

    char* ws = (char*)d_ws;
    size_t off = 0;
    unsigned short* ha = (unsigned short*)(ws + off); off += (size_t)N * 64 * 2;
    unsigned short* hb = (unsigned short*)(ws + off); off += (size_t)N * 64 * 2;
    float* na_  = (float*)(ws + off); off += (size_t)N * sizeof(float);
    float* nb_  = (float*)(ws + off); off += (size_t)N * sizeof(float);
    int*   ptr  = (int*)  (ws + off); off += (size_t)(N + 1) * sizeof(int);
    off = (off + 15) & ~(size_t)15;
    int*   perm = (int*)  (ws + off); off += (size_t)N * sizeof(int);
    (void)ws_size; (void)n_in; (void)out_size;

    build_rowptr_scan<<<(E + 255) / 256, 256, 0, stream>>>(row, ptr, N, E);

    // segment-local degree sort (all atomics in LDS), 1024-node segments
    build_perm_seg<<<(N + PSEG - 1) / PSEG, 1024, 0, stream>>>(ptr, perm, N);

    const int nbG = (N + 127) / 128;
    gemm1_relu<<<nbG, 256, 0, stream>>>(x, W1, b1, ha, na_, N);

    const int nb16 = (N + 15) / 16;
    unsigned short* hc = ha; unsigned short* hn = hb;
    float* nc = na_; float* nn = nb_;
    for (int l = 0; l < 4; ++l) {
        agnn_layer<<<nb16, 256, 0, stream>>>((const uint4*)hc, nc, ptr, col, perm,
                                             (uint4*)hn, nn, N);
        unsigned short* t = hc; hc = hn; hn = t;
        float* tf = nc; nc = nn; nn = tf;
    }

    gemm2<<<nbG, 256, 0, stream>>>(hc, nc, W2, b2, out, N);
}

// Round 2
// 301.892 us; speedup vs baseline: 1.0073x; 1.0073x over previous
//
#include <hip/hip_runtime.h>

// ---------------------------------------------------------------------------
// AGNN: h = relu(x@W1^T+b1); 4x [ h = relu(agnn(h)) ]; out = h@W2^T+b2
// N=100000, E=1600000, IN=128, HID=OUT=64, float32 in/out.
// Between layers: xn = h/(||h||+eps) stored FP16 (128 B/row) + nrm f32.
//   p = exp2( dot(xn_i * log2e, xn_j) );  out_i = sum p * nrm_j * xn_j / sum p
// agnn: nodes processed in SEGMENT-LOCAL degree-sorted order (perm).
// Round 2:
//   - gemm1/gemm2: 512-thread blocks (8 waves), tile 128x64, 4x4/thread
//     -> 24 waves/CU instead of 12 (round-1 was latency-bound at Occ=23%)
//   - gemm1: register-prefetch of next K-chunk overlapping compute
//   - rowptr O(E) scan + 1024-seg counting sort kept from round 1
//   - agnn kernel untouched (full occupancy, ~5 TB/s effective gather)
// ---------------------------------------------------------------------------

typedef _Float16 h2 __attribute__((ext_vector_type(2)));

union U4H { uint4 u; h2 h[4]; };
union U2H { uint2 u; h2 h[2]; };
union UHI { unsigned u; h2 h; };

#define DEV_INLINE __device__ __forceinline__

DEV_INLINE h2 mkh2(float a, float b) {
    h2 r; r.x = (_Float16)a; r.y = (_Float16)b; return r;
}

// ptr[i] = lower_bound(row, i). Thread e covers i in (row[e-1], row[e]].
__global__ __launch_bounds__(256) void build_rowptr_scan(const int* __restrict__ row,
                                                         int* __restrict__ ptr,
                                                         int N, int E) {
    int e = blockIdx.x * blockDim.x + threadIdx.x;
    if (e >= E) return;
    const int r1 = row[e];
    const int r0 = (e == 0) ? -1 : row[e - 1];
    for (int i = r0 + 1; i <= r1; ++i) ptr[i] = e;
    if (e == E - 1) {
        for (int i = r1 + 1; i <= N; ++i) ptr[i] = E;
    }
}

// Segment-local counting sort by degree. One 1024-thread block per 1024-node
// segment (1 node per thread); 256-bucket LDS histogram + 8-step scan.
#define PSEG 1024
__global__ __launch_bounds__(1024) void build_perm_seg(const int* __restrict__ ptr,
                                                       int* __restrict__ perm,
                                                       int N) {
    __shared__ int hist[256];
    __shared__ int tmp[256];
    const int t    = threadIdx.x;
    const int base = blockIdx.x * PSEG;
    const int end  = (base + PSEG < N) ? base + PSEG : N;
    const int cnt  = end - base;

    if (t < 256) hist[t] = 0;
    __syncthreads();

    int d = -1;
    if (t < cnt) {
        d = ptr[base + t + 1] - ptr[base + t];
        if (d > 255) d = 255;
        atomicAdd(&hist[d], 1);
    }
    __syncthreads();

    int h0 = (t < 256) ? hist[t] : 0;
    int* src = hist; int* dst = tmp;
    for (int off = 1; off < 256; off <<= 1) {
        if (t < 256) dst[t] = src[t] + (t >= off ? src[t - off] : 0);
        __syncthreads();
        int* tt = src; src = dst; dst = tt;
    }
    if (t < 256) src[t] -= h0;
    __syncthreads();

    if (t < cnt) {
        int pos = base + atomicAdd(&src[d], 1);
        perm[pos] = base + t;
    }
}

// r = relu(x[i,:128]@W1^T + b1); xn[i]=f16(r/(||r||+eps)); nrm[i]=||r||+eps
// 512 threads, tile 128 nodes x 64 outs, thread = 4 nodes x 4 outs.
// K staged in four 32-chunks; next chunk's global loads issued before compute.
__global__ __launch_bounds__(512) void gemm1_relu(const float* __restrict__ x,
                                                  const float* __restrict__ W1,
                                                  const float* __restrict__ b1,
                                                  unsigned short* __restrict__ xn,
                                                  float* __restrict__ nrm,
                                                  int N) {
    __shared__ __align__(16) float Wt[32 * 64];    // 8 KiB
    __shared__ __align__(16) float xT[32 * 128];   // 16 KiB
    const int tid  = threadIdx.x;
    const int tx   = tid & 15;    // 4 outs at 4*tx
    const int ty   = tid >> 4;    // 4 nodes at 4*ty, ty in [0,32)
    const int base = blockIdx.x * 128;

    const float4* W4  = (const float4*)W1;
    const float4* x4p = (const float4*)x;

    // staging indices (fixed per thread)
    const int wO  = tid & 63;          // W: output column
    const int wK4 = tid >> 6;          // W: k4 in [0,8)
    const int mA  = tid & 127;         // x idx A: node offset
    const int kA  = tid >> 7;          // k4 in [0,4)
    const int mB  = mA;                // x idx B = tid + 512
    const int kB  = kA + 4;            // k4 in [4,8)
    const int nodeA = base + mA;

    float4 wv, xa_, xb_;
    // prefetch chunk 0
    wv = W4[wO * 32 + wK4];
    xa_ = make_float4(0.f, 0.f, 0.f, 0.f);
    xb_ = xa_;
    if (nodeA < N) {
        xa_ = x4p[(size_t)nodeA * 32 + kA];
        xb_ = x4p[(size_t)nodeA * 32 + kB];
    }

    float4 b4 = ((const float4*)b1)[tx];
    float4 acc[4];
    acc[0] = b4; acc[1] = b4; acc[2] = b4; acc[3] = b4;

    for (int c = 0; c < 4; ++c) {
        // write staged registers -> LDS (waits on the in-flight loads)
        Wt[(4 * wK4 + 0) * 64 + wO] = wv.x;
        Wt[(4 * wK4 + 1) * 64 + wO] = wv.y;
        Wt[(4 * wK4 + 2) * 64 + wO] = wv.z;
        Wt[(4 * wK4 + 3) * 64 + wO] = wv.w;
        xT[(4 * kA + 0) * 128 + mA] = xa_.x;
        xT[(4 * kA + 1) * 128 + mA] = xa_.y;
        xT[(4 * kA + 2) * 128 + mA] = xa_.z;
        xT[(4 * kA + 3) * 128 + mA] = xa_.w;
        xT[(4 * kB + 0) * 128 + mB] = xb_.x;
        xT[(4 * kB + 1) * 128 + mB] = xb_.y;
        xT[(4 * kB + 2) * 128 + mB] = xb_.z;
        xT[(4 * kB + 3) * 128 + mB] = xb_.w;
        __syncthreads();

        // issue next chunk's loads (consumed at next iteration's LDS write)
        if (c < 3) {
            const int ko = (c + 1) * 8;   // chunk offset in float4 units
            wv = W4[wO * 32 + ko + wK4];
            if (nodeA < N) {
                xa_ = x4p[(size_t)nodeA * 32 + ko + kA];
                xb_ = x4p[(size_t)nodeA * 32 + ko + kB];
            }
        }

        // compute this chunk
#pragma unroll 4
        for (int k = 0; k < 32; ++k) {
            const float4 w4 = *(const float4*)&Wt[k * 64 + 4 * tx];
            const float4 xv = *(const float4*)&xT[k * 128 + 4 * ty];
            acc[0].x = fmaf(xv.x, w4.x, acc[0].x);
            acc[0].y = fmaf(xv.x, w4.y, acc[0].y);
            acc[0].z = fmaf(xv.x, w4.z, acc[0].z);
            acc[0].w = fmaf(xv.x, w4.w, acc[0].w);
            acc[1].x = fmaf(xv.y, w4.x, acc[1].x);
            acc[1].y = fmaf(xv.y, w4.y, acc[1].y);
            acc[1].z = fmaf(xv.y, w4.z, acc[1].z);
            acc[1].w = fmaf(xv.y, w4.w, acc[1].w);
            acc[2].x = fmaf(xv.z, w4.x, acc[2].x);
            acc[2].y = fmaf(xv.z, w4.y, acc[2].y);
            acc[2].z = fmaf(xv.z, w4.z, acc[2].z);
            acc[2].w = fmaf(xv.z, w4.w, acc[2].w);
            acc[3].x = fmaf(xv.w, w4.x, acc[3].x);
            acc[3].y = fmaf(xv.w, w4.y, acc[3].y);
            acc[3].z = fmaf(xv.w, w4.z, acc[3].z);
            acc[3].w = fmaf(xv.w, w4.w, acc[3].w);
        }
        if (c < 3) __syncthreads();
    }

#pragma unroll
    for (int mm = 0; mm < 4; ++mm) {
        float4 r = acc[mm];
        r.x = fmaxf(r.x, 0.f); r.y = fmaxf(r.y, 0.f);
        r.z = fmaxf(r.z, 0.f); r.w = fmaxf(r.w, 0.f);
        float s = fmaf(r.x, r.x, fmaf(r.y, r.y, fmaf(r.z, r.z, r.w * r.w)));
        s += __shfl_xor(s, 1, 64);
        s += __shfl_xor(s, 2, 64);
        s += __shfl_xor(s, 4, 64);
        s += __shfl_xor(s, 8, 64);
        const float nn  = sqrtf(s) + 1e-12f;
        const float inv = 1.f / nn;
        int node = base + 4 * ty + mm;
        if (node < N) {
            U2H pk;
            pk.h[0] = mkh2(r.x * inv, r.y * inv);
            pk.h[1] = mkh2(r.z * inv, r.w * inv);
            *(uint2*)&xn[(size_t)node * 64 + 4 * tx] = pk.u;
            if (tx == mm) nrm[node] = nn;
        }
    }
}

// 4 nodes per wave (16 lanes each, degree-sorted); 2 edge-groups x 8 lanes;
// 2 edges in flight per group.  (UNCHANGED.)
__global__ __launch_bounds__(256) void agnn_layer(const uint4* __restrict__ xn4,
                                                  const float* __restrict__ nrm,
                                                  const int* __restrict__ ptr,
                                                  const int* __restrict__ col,
                                                  const int* __restrict__ perm,
                                                  uint4* __restrict__ xo4,
                                                  float* __restrict__ nrmo,
                                                  int N) {
    const int tid  = threadIdx.x;
    const int lane = tid & 63;
    const int g    = (lane >> 3) & 1;   // edge group 0..1 within 16-lane quarter
    const int sub  = lane & 7;          // 16B chunk of the 128B row
    const int slot = blockIdx.x * 16 + (tid >> 4);
    if (slot >= N) return;
    const int i = perm[slot];

    U4H hi_;
    hi_.u = xn4[(unsigned)i * 8u + sub];
    {
        const _Float16 L2E = (_Float16)1.4426950408889634f;
        h2 l2 = {L2E, L2E};
#pragma unroll
        for (int t = 0; t < 4; ++t) hi_.h[t] *= l2;   // p = exp2(dot)
    }

    const int p0 = ptr[i], p1 = ptr[i + 1];

    float den = 0.f;
    U4H acc;
    acc.h[0] = mkh2(0.f, 0.f); acc.h[1] = mkh2(0.f, 0.f);
    acc.h[2] = mkh2(0.f, 0.f); acc.h[3] = mkh2(0.f, 0.f);

#define EDGE_BODY(VU, NRMJ)                                                  \
    {                                                                        \
        U4H xa; xa.u = (VU);                                                 \
        float s = 0.f;                                                       \
        s = __builtin_amdgcn_fdot2(hi_.h[0], xa.h[0], s, false);             \
        s = __builtin_amdgcn_fdot2(hi_.h[1], xa.h[1], s, false);             \
        s = __builtin_amdgcn_fdot2(hi_.h[2], xa.h[2], s, false);             \
        s = __builtin_amdgcn_fdot2(hi_.h[3], xa.h[3], s, false);             \
        s += __shfl_xor(s, 1, 64);                                           \
        s += __shfl_xor(s, 2, 64);                                           \
        s += __shfl_xor(s, 4, 64);                                           \
        const float p = exp2f(s);                                            \
        den += p;                                                            \
        const _Float16 wh = (_Float16)(p * (NRMJ));                          \
        h2 w2 = {wh, wh};                                                    \
        acc.h[0] += w2 * xa.h[0];                                            \
        acc.h[1] += w2 * xa.h[1];                                            \
        acc.h[2] += w2 * xa.h[2];                                            \
        acc.h[3] += w2 * xa.h[3];                                            \
    }

    int e = p0 + g;
    for (; e + 2 < p1; e += 4) {          // 2 edges per group in flight
        const int ja = col[e];
        const int jb = col[e + 2];
        const uint4 va = xn4[(unsigned)ja * 8u + sub];
        const uint4 vb = xn4[(unsigned)jb * 8u + sub];
        const float na = nrm[ja];
        const float nb = nrm[jb];
        EDGE_BODY(va, na)
        EDGE_BODY(vb, nb)
    }
    if (e < p1) {
        const int j = col[e];
        const uint4 v = xn4[(unsigned)j * 8u + sub];
        const float nj = nrm[j];
        EDGE_BODY(v, nj)
    }
#undef EDGE_BODY

    // merge the 2 edge-groups (within the 16-lane quarter): xor 8
    {
        den += __shfl_xor(den, 8, 64);
#pragma unroll
        for (int t = 0; t < 4; ++t) {
            UHI a; a.h = acc.h[t];
            UHI b; b.u = (unsigned)__shfl_xor((int)a.u, 8, 64);
            acc.h[t] = a.h + b.h;
        }
    }

    const float id = 1.f / fmaxf(den, 1e-12f);
    float o[8];
#pragma unroll
    for (int t = 0; t < 4; ++t) {
        o[2 * t]     = fmaxf((float)acc.h[t].x * id, 0.f);
        o[2 * t + 1] = fmaxf((float)acc.h[t].y * id, 0.f);
    }

    float s2 = 0.f;
#pragma unroll
    for (int t = 0; t < 8; ++t) s2 = fmaf(o[t], o[t], s2);
    s2 += __shfl_xor(s2, 1, 64);
    s2 += __shfl_xor(s2, 2, 64);
    s2 += __shfl_xor(s2, 4, 64);
    const float nn  = sqrtf(s2) + 1e-12f;
    const float inv = 1.f / nn;

    if (g == 0) {
        U4H ov;
        ov.h[0] = mkh2(o[0] * inv, o[1] * inv);
        ov.h[1] = mkh2(o[2] * inv, o[3] * inv);
        ov.h[2] = mkh2(o[4] * inv, o[5] * inv);
        ov.h[3] = mkh2(o[6] * inv, o[7] * inv);
        xo4[(unsigned)i * 8u + sub] = ov.u;
        if (sub == 0) nrmo[i] = nn;
    }
}

// out[i,:64] = (xn[i]*nrm[i]) @ W2^T + b2   (f32 out)
// 512 threads, tile 128 nodes x 64 outs, thread = 4 nodes x 4 outs.
__global__ __launch_bounds__(512) void gemm2(const unsigned short* __restrict__ xn,
                                             const float* __restrict__ nrm,
                                             const float* __restrict__ W2,
                                             const float* __restrict__ b2,
                                             float* __restrict__ out,
                                             int N) {
    __shared__ __align__(16) float Wt[64 * 64];    // 16 KiB
    __shared__ __align__(16) float xT[64 * 128];   // 32 KiB
    const int tid  = threadIdx.x;
    const int tx   = tid & 15;
    const int ty   = tid >> 4;    // [0,32)
    const int base = blockIdx.x * 128;

    {
        const float4* W4 = (const float4*)W2;
#pragma unroll
        for (int it = 0; it < 2; ++it) {
            int idx = tid + it * 512;              // 1024 total
            int o = idx & 63, k4 = idx >> 6;       // k4 in [0,16)
            float4 v = W4[o * 16 + k4];
            Wt[(4 * k4 + 0) * 64 + o] = v.x;
            Wt[(4 * k4 + 1) * 64 + o] = v.y;
            Wt[(4 * k4 + 2) * 64 + o] = v.z;
            Wt[(4 * k4 + 3) * 64 + o] = v.w;
        }
        const uint2* x2 = (const uint2*)xn;
#pragma unroll
        for (int it = 0; it < 4; ++it) {
            int idx = tid + it * 512;              // 2048 total
            int mm = idx & 127, k4 = idx >> 7;     // k4 in [0,16)
            int node = base + mm;
            U2H v; v.u = make_uint2(0u, 0u);
            float nn = 0.f;
            if (node < N) { v.u = x2[(size_t)node * 16 + k4]; nn = nrm[node]; }
            xT[(4 * k4 + 0) * 128 + mm] = (float)v.h[0].x * nn;
            xT[(4 * k4 + 1) * 128 + mm] = (float)v.h[0].y * nn;
            xT[(4 * k4 + 2) * 128 + mm] = (float)v.h[1].x * nn;
            xT[(4 * k4 + 3) * 128 + mm] = (float)v.h[1].y * nn;
        }
    }
    __syncthreads();

    float4 b4 = ((const float4*)b2)[tx];
    float4 acc[4];
    acc[0] = b4; acc[1] = b4; acc[2] = b4; acc[3] = b4;

#pragma unroll 4
    for (int k = 0; k < 64; ++k) {
        const float4 w4 = *(const float4*)&Wt[k * 64 + 4 * tx];
        const float4 xv = *(const float4*)&xT[k * 128 + 4 * ty];
        acc[0].x = fmaf(xv.x, w4.x, acc[0].x);
        acc[0].y = fmaf(xv.x, w4.y, acc[0].y);
        acc[0].z = fmaf(xv.x, w4.z, acc[0].z);
        acc[0].w = fmaf(xv.x, w4.w, acc[0].w);
        acc[1].x = fmaf(xv.y, w4.x, acc[1].x);
        acc[1].y = fmaf(xv.y, w4.y, acc[1].y);
        acc[1].z = fmaf(xv.y, w4.z, acc[1].z);
        acc[1].w = fmaf(xv.y, w4.w, acc[1].w);
        acc[2].x = fmaf(xv.z, w4.x, acc[2].x);
        acc[2].y = fmaf(xv.z, w4.y, acc[2].y);
        acc[2].z = fmaf(xv.z, w4.z, acc[2].z);
        acc[2].w = fmaf(xv.z, w4.w, acc[2].w);
        acc[3].x = fmaf(xv.w, w4.x, acc[3].x);
        acc[3].y = fmaf(xv.w, w4.y, acc[3].y);
        acc[3].z = fmaf(xv.w, w4.z, acc[3].z);
        acc[3].w = fmaf(xv.w, w4.w, acc[3].w);
    }

#pragma unroll
    for (int mm = 0; mm < 4; ++mm) {
        int node = base + 4 * ty + mm;
        if (node < N) *(float4*)&out[(size_t)node * 64 + 4 * tx] = acc[mm];
    }
}

extern "C" void kernel_launch(void* const* d_in, const int* in_sizes, int n_in,
                              void* d_out, int out_size, void* d_ws, size_t ws_size,
                              hipStream_t stream) {
    const float* x   = (const float*)d_in[0];
    const int*   row = (const int*)d_in[1];
    const int*   col = (const int*)d_in[2];
    const float* W1  = (const float*)d_in[3];
    const float* b1  = (const float*)d_in[4];
    const float* W2  = (const float*)d_in[5];
    const float* b2  = (const float*)d_in[6];
    float* out = (float*)d_out;

    const int N = in_sizes[0] / 128;
    const int E = in_sizes[1];

    char* ws = (char*)d_ws;
    size_t off = 0;
    unsigned short* ha = (unsigned short*)(ws + off); off += (size_t)N * 64 * 2;
    unsigned short* hb = (unsigned short*)(ws + off); off += (size_t)N * 64 * 2;
    float* na_  = (float*)(ws + off); off += (size_t)N * sizeof(float);
    float* nb_  = (float*)(ws + off); off += (size_t)N * sizeof(float);
    int*   ptr  = (int*)  (ws + off); off += (size_t)(N + 1) * sizeof(int);
    off = (off + 15) & ~(size_t)15;
    int*   perm = (int*)  (ws + off); off += (size_t)N * sizeof(int);
    (void)ws_size; (void)n_in; (void)out_size;

    build_rowptr_scan<<<(E + 255) / 256, 256, 0, stream>>>(row, ptr, N, E);

    // segment-local degree sort (all atomics in LDS), 1024-node segments
    build_perm_seg<<<(N + PSEG - 1) / PSEG, 1024, 0, stream>>>(ptr, perm, N);

    const int nbG = (N + 127) / 128;
    gemm1_relu<<<nbG, 512, 0, stream>>>(x, W1, b1, ha, na_, N);

    const int nb16 = (N + 15) / 16;
    unsigned short* hc = ha; unsigned short* hn = hb;
    float* nc = na_; float* nn = nb_;
    for (int l = 0; l < 4; ++l) {
        agnn_layer<<<nb16, 256, 0, stream>>>((const uint4*)hc, nc, ptr, col, perm,
                                             (uint4*)hn, nn, N);
        unsigned short* t = hc; hc = hn; hn = t;
        float* tf = nc; nc = nn; nn = tf;
    }

    gemm2<<<nbG, 512, 0, stream>>>(hc, nc, W2, b2, out, N);
}

// Round 3
// 300.380 us; speedup vs baseline: 1.0123x; 1.0050x over previous
//
#include <hip/hip_runtime.h>

// ---------------------------------------------------------------------------
// AGNN: h = relu(x@W1^T+b1); 4x [ h = relu(agnn(h)) ]; out = h@W2^T+b2
// N=100000, E=1600000, IN=128, HID=OUT=64, float32 in/out.
// Between layers: xn = h/(||h||+eps) stored FP16 (128 B/row) + nrm f32.
//   p = exp2( dot(xn_i * log2e, xn_j) );  out_i = sum p * nrm_j * xn_j / sum p
// agnn: nodes processed in SEGMENT-LOCAL degree-sorted order (perm).
// Round 3:
//   - agnn inner loop: 2-stage software pipeline (indices 2 ahead, rows 1
//     ahead of compute); contiguous half-split of edge list per 8-lane group
//     (round-2 profile: 40.6 us/layer, VALU 38%, HBM 35%, Occ 47% = latency
//     bound on the col->xn dependent chain, fully drained each iteration)
//   - gemm1/gemm2 (512 thr, prefetch), rowptr scan, 1024-seg sort unchanged
// ---------------------------------------------------------------------------

typedef _Float16 h2 __attribute__((ext_vector_type(2)));

union U4H { uint4 u; h2 h[4]; };
union U2H { uint2 u; h2 h[2]; };
union UHI { unsigned u; h2 h; };

#define DEV_INLINE __device__ __forceinline__

DEV_INLINE h2 mkh2(float a, float b) {
    h2 r; r.x = (_Float16)a; r.y = (_Float16)b; return r;
}

// ptr[i] = lower_bound(row, i). Thread e covers i in (row[e-1], row[e]].
__global__ __launch_bounds__(256) void build_rowptr_scan(const int* __restrict__ row,
                                                         int* __restrict__ ptr,
                                                         int N, int E) {
    int e = blockIdx.x * blockDim.x + threadIdx.x;
    if (e >= E) return;
    const int r1 = row[e];
    const int r0 = (e == 0) ? -1 : row[e - 1];
    for (int i = r0 + 1; i <= r1; ++i) ptr[i] = e;
    if (e == E - 1) {
        for (int i = r1 + 1; i <= N; ++i) ptr[i] = E;
    }
}

// Segment-local counting sort by degree. One 1024-thread block per 1024-node
// segment (1 node per thread); 256-bucket LDS histogram + 8-step scan.
#define PSEG 1024
__global__ __launch_bounds__(1024) void build_perm_seg(const int* __restrict__ ptr,
                                                       int* __restrict__ perm,
                                                       int N) {
    __shared__ int hist[256];
    __shared__ int tmp[256];
    const int t    = threadIdx.x;
    const int base = blockIdx.x * PSEG;
    const int end  = (base + PSEG < N) ? base + PSEG : N;
    const int cnt  = end - base;

    if (t < 256) hist[t] = 0;
    __syncthreads();

    int d = -1;
    if (t < cnt) {
        d = ptr[base + t + 1] - ptr[base + t];
        if (d > 255) d = 255;
        atomicAdd(&hist[d], 1);
    }
    __syncthreads();

    int h0 = (t < 256) ? hist[t] : 0;
    int* src = hist; int* dst = tmp;
    for (int off = 1; off < 256; off <<= 1) {
        if (t < 256) dst[t] = src[t] + (t >= off ? src[t - off] : 0);
        __syncthreads();
        int* tt = src; src = dst; dst = tt;
    }
    if (t < 256) src[t] -= h0;
    __syncthreads();

    if (t < cnt) {
        int pos = base + atomicAdd(&src[d], 1);
        perm[pos] = base + t;
    }
}

// r = relu(x[i,:128]@W1^T + b1); xn[i]=f16(r/(||r||+eps)); nrm[i]=||r||+eps
// 512 threads, tile 128 nodes x 64 outs, thread = 4 nodes x 4 outs.
// K staged in four 32-chunks; next chunk's global loads issued before compute.
__global__ __launch_bounds__(512) void gemm1_relu(const float* __restrict__ x,
                                                  const float* __restrict__ W1,
                                                  const float* __restrict__ b1,
                                                  unsigned short* __restrict__ xn,
                                                  float* __restrict__ nrm,
                                                  int N) {
    __shared__ __align__(16) float Wt[32 * 64];    // 8 KiB
    __shared__ __align__(16) float xT[32 * 128];   // 16 KiB
    const int tid  = threadIdx.x;
    const int tx   = tid & 15;    // 4 outs at 4*tx
    const int ty   = tid >> 4;    // 4 nodes at 4*ty, ty in [0,32)
    const int base = blockIdx.x * 128;

    const float4* W4  = (const float4*)W1;
    const float4* x4p = (const float4*)x;

    const int wO  = tid & 63;          // W: output column
    const int wK4 = tid >> 6;          // W: k4 in [0,8)
    const int mA  = tid & 127;         // x idx: node offset
    const int kA  = tid >> 7;          // k4 in [0,4)
    const int mB  = mA;
    const int kB  = kA + 4;            // k4 in [4,8)
    const int nodeA = base + mA;

    float4 wv, xa_, xb_;
    wv = W4[wO * 32 + wK4];
    xa_ = make_float4(0.f, 0.f, 0.f, 0.f);
    xb_ = xa_;
    if (nodeA < N) {
        xa_ = x4p[(size_t)nodeA * 32 + kA];
        xb_ = x4p[(size_t)nodeA * 32 + kB];
    }

    float4 b4 = ((const float4*)b1)[tx];
    float4 acc[4];
    acc[0] = b4; acc[1] = b4; acc[2] = b4; acc[3] = b4;

    for (int c = 0; c < 4; ++c) {
        Wt[(4 * wK4 + 0) * 64 + wO] = wv.x;
        Wt[(4 * wK4 + 1) * 64 + wO] = wv.y;
        Wt[(4 * wK4 + 2) * 64 + wO] = wv.z;
        Wt[(4 * wK4 + 3) * 64 + wO] = wv.w;
        xT[(4 * kA + 0) * 128 + mA] = xa_.x;
        xT[(4 * kA + 1) * 128 + mA] = xa_.y;
        xT[(4 * kA + 2) * 128 + mA] = xa_.z;
        xT[(4 * kA + 3) * 128 + mA] = xa_.w;
        xT[(4 * kB + 0) * 128 + mB] = xb_.x;
        xT[(4 * kB + 1) * 128 + mB] = xb_.y;
        xT[(4 * kB + 2) * 128 + mB] = xb_.z;
        xT[(4 * kB + 3) * 128 + mB] = xb_.w;
        __syncthreads();

        if (c < 3) {
            const int ko = (c + 1) * 8;
            wv = W4[wO * 32 + ko + wK4];
            if (nodeA < N) {
                xa_ = x4p[(size_t)nodeA * 32 + ko + kA];
                xb_ = x4p[(size_t)nodeA * 32 + ko + kB];
            }
        }

#pragma unroll 4
        for (int k = 0; k < 32; ++k) {
            const float4 w4 = *(const float4*)&Wt[k * 64 + 4 * tx];
            const float4 xv = *(const float4*)&xT[k * 128 + 4 * ty];
            acc[0].x = fmaf(xv.x, w4.x, acc[0].x);
            acc[0].y = fmaf(xv.x, w4.y, acc[0].y);
            acc[0].z = fmaf(xv.x, w4.z, acc[0].z);
            acc[0].w = fmaf(xv.x, w4.w, acc[0].w);
            acc[1].x = fmaf(xv.y, w4.x, acc[1].x);
            acc[1].y = fmaf(xv.y, w4.y, acc[1].y);
            acc[1].z = fmaf(xv.y, w4.z, acc[1].z);
            acc[1].w = fmaf(xv.y, w4.w, acc[1].w);
            acc[2].x = fmaf(xv.z, w4.x, acc[2].x);
            acc[2].y = fmaf(xv.z, w4.y, acc[2].y);
            acc[2].z = fmaf(xv.z, w4.z, acc[2].z);
            acc[2].w = fmaf(xv.z, w4.w, acc[2].w);
            acc[3].x = fmaf(xv.w, w4.x, acc[3].x);
            acc[3].y = fmaf(xv.w, w4.y, acc[3].y);
            acc[3].z = fmaf(xv.w, w4.z, acc[3].z);
            acc[3].w = fmaf(xv.w, w4.w, acc[3].w);
        }
        if (c < 3) __syncthreads();
    }

#pragma unroll
    for (int mm = 0; mm < 4; ++mm) {
        float4 r = acc[mm];
        r.x = fmaxf(r.x, 0.f); r.y = fmaxf(r.y, 0.f);
        r.z = fmaxf(r.z, 0.f); r.w = fmaxf(r.w, 0.f);
        float s = fmaf(r.x, r.x, fmaf(r.y, r.y, fmaf(r.z, r.z, r.w * r.w)));
        s += __shfl_xor(s, 1, 64);
        s += __shfl_xor(s, 2, 64);
        s += __shfl_xor(s, 4, 64);
        s += __shfl_xor(s, 8, 64);
        const float nn  = sqrtf(s) + 1e-12f;
        const float inv = 1.f / nn;
        int node = base + 4 * ty + mm;
        if (node < N) {
            U2H pk;
            pk.h[0] = mkh2(r.x * inv, r.y * inv);
            pk.h[1] = mkh2(r.z * inv, r.w * inv);
            *(uint2*)&xn[(size_t)node * 64 + 4 * tx] = pk.u;
            if (tx == mm) nrm[node] = nn;
        }
    }
}

// 4 nodes per wave (16 lanes each, degree-sorted); 2 edge-groups x 8 lanes,
// each group takes a CONTIGUOUS half of the edge list; 2-stage software
// pipeline: indices 2 pairs ahead, rows 1 pair ahead of compute.
__global__ __launch_bounds__(256) void agnn_layer(const uint4* __restrict__ xn4,
                                                  const float* __restrict__ nrm,
                                                  const int* __restrict__ ptr,
                                                  const int* __restrict__ col,
                                                  const int* __restrict__ perm,
                                                  uint4* __restrict__ xo4,
                                                  float* __restrict__ nrmo,
                                                  int N) {
    const int tid  = threadIdx.x;
    const int lane = tid & 63;
    const int g    = (lane >> 3) & 1;   // edge group 0..1 within 16-lane quarter
    const int sub  = lane & 7;          // 16B chunk of the 128B row
    const int slot = blockIdx.x * 16 + (tid >> 4);
    if (slot >= N) return;
    const int i = perm[slot];

    U4H hi_;
    hi_.u = xn4[(unsigned)i * 8u + sub];
    {
        const _Float16 L2E = (_Float16)1.4426950408889634f;
        h2 l2 = {L2E, L2E};
#pragma unroll
        for (int t = 0; t < 4; ++t) hi_.h[t] *= l2;   // p = exp2(dot)
    }

    const int p0  = ptr[i], p1 = ptr[i + 1];
    const int mid = p0 + ((p1 - p0 + 1) >> 1);
    int       t   = g ? mid : p0;
    const int e_  = g ? p1  : mid;

    float den = 0.f;
    U4H acc;
    acc.h[0] = mkh2(0.f, 0.f); acc.h[1] = mkh2(0.f, 0.f);
    acc.h[2] = mkh2(0.f, 0.f); acc.h[3] = mkh2(0.f, 0.f);

#define EDGE_BODY(VU, NRMJ)                                                  \
    {                                                                        \
        U4H xa; xa.u = (VU);                                                 \
        float s = 0.f;                                                       \
        s = __builtin_amdgcn_fdot2(hi_.h[0], xa.h[0], s, false);             \
        s = __builtin_amdgcn_fdot2(hi_.h[1], xa.h[1], s, false);             \
        s = __builtin_amdgcn_fdot2(hi_.h[2], xa.h[2], s, false);             \
        s = __builtin_amdgcn_fdot2(hi_.h[3], xa.h[3], s, false);             \
        s += __shfl_xor(s, 1, 64);                                           \
        s += __shfl_xor(s, 2, 64);                                           \
        s += __shfl_xor(s, 4, 64);                                           \
        const float p = exp2f(s);                                            \
        den += p;                                                            \
        const _Float16 wh = (_Float16)(p * (NRMJ));                          \
        h2 w2 = {wh, wh};                                                    \
        acc.h[0] += w2 * xa.h[0];                                            \
        acc.h[1] += w2 * xa.h[1];                                            \
        acc.h[2] += w2 * xa.h[2];                                            \
        acc.h[3] += w2 * xa.h[3];                                            \
    }

    {
        const int n_ = e_ - t;
        int j0 = 0, j1 = 0, j2 = 0, j3 = 0;
        uint4 v0 = make_uint4(0u, 0u, 0u, 0u), v1 = v0;
        float n0 = 0.f, n1 = 0.f;
        if (n_ > 0) j0 = col[t];
        if (n_ > 1) j1 = col[t + 1];
        if (n_ > 0) { v0 = xn4[(unsigned)j0 * 8u + sub]; n0 = nrm[j0]; }
        if (n_ > 1) { v1 = xn4[(unsigned)j1 * 8u + sub]; n1 = nrm[j1]; }
        if (n_ > 2) j2 = col[t + 2];
        if (n_ > 3) j3 = col[t + 3];

        while (t + 5 < e_) {
            const uint4 v2 = xn4[(unsigned)j2 * 8u + sub];
            const float m2 = nrm[j2];
            const uint4 v3 = xn4[(unsigned)j3 * 8u + sub];
            const float m3 = nrm[j3];
            const int j4 = col[t + 4];
            const int j5 = col[t + 5];
            EDGE_BODY(v0, n0)
            EDGE_BODY(v1, n1)
            v0 = v2; n0 = m2; v1 = v3; n1 = m3;
            j2 = j4; j3 = j5;
            t += 2;
        }
        const int rem = e_ - t;   // 0..5
        if (rem > 2) {
            const uint4 v2 = xn4[(unsigned)j2 * 8u + sub];
            const float m2 = nrm[j2];
            uint4 v3 = make_uint4(0u, 0u, 0u, 0u);
            float m3 = 0.f;
            if (rem > 3) { v3 = xn4[(unsigned)j3 * 8u + sub]; m3 = nrm[j3]; }
            int j4 = 0;
            if (rem > 4) j4 = col[t + 4];
            EDGE_BODY(v0, n0)
            EDGE_BODY(v1, n1)
            EDGE_BODY(v2, m2)
            if (rem > 3) EDGE_BODY(v3, m3)
            if (rem > 4) {
                const uint4 v4 = xn4[(unsigned)j4 * 8u + sub];
                const float m4 = nrm[j4];
                EDGE_BODY(v4, m4)
            }
        } else {
            if (rem > 0) EDGE_BODY(v0, n0)
            if (rem > 1) EDGE_BODY(v1, n1)
        }
    }
#undef EDGE_BODY

    // merge the 2 edge-groups (within the 16-lane quarter): xor 8
    {
        den += __shfl_xor(den, 8, 64);
#pragma unroll
        for (int t2 = 0; t2 < 4; ++t2) {
            UHI a; a.h = acc.h[t2];
            UHI b; b.u = (unsigned)__shfl_xor((int)a.u, 8, 64);
            acc.h[t2] = a.h + b.h;
        }
    }

    const float id = 1.f / fmaxf(den, 1e-12f);
    float o[8];
#pragma unroll
    for (int t2 = 0; t2 < 4; ++t2) {
        o[2 * t2]     = fmaxf((float)acc.h[t2].x * id, 0.f);
        o[2 * t2 + 1] = fmaxf((float)acc.h[t2].y * id, 0.f);
    }

    float s2 = 0.f;
#pragma unroll
    for (int t2 = 0; t2 < 8; ++t2) s2 = fmaf(o[t2], o[t2], s2);
    s2 += __shfl_xor(s2, 1, 64);
    s2 += __shfl_xor(s2, 2, 64);
    s2 += __shfl_xor(s2, 4, 64);
    const float nn  = sqrtf(s2) + 1e-12f;
    const float inv = 1.f / nn;

    if (g == 0) {
        U4H ov;
        ov.h[0] = mkh2(o[0] * inv, o[1] * inv);
        ov.h[1] = mkh2(o[2] * inv, o[3] * inv);
        ov.h[2] = mkh2(o[4] * inv, o[5] * inv);
        ov.h[3] = mkh2(o[6] * inv, o[7] * inv);
        xo4[(unsigned)i * 8u + sub] = ov.u;
        if (sub == 0) nrmo[i] = nn;
    }
}

// out[i,:64] = (xn[i]*nrm[i]) @ W2^T + b2   (f32 out)
// 512 threads, tile 128 nodes x 64 outs, thread = 4 nodes x 4 outs.
__global__ __launch_bounds__(512) void gemm2(const unsigned short* __restrict__ xn,
                                             const float* __restrict__ nrm,
                                             const float* __restrict__ W2,
                                             const float* __restrict__ b2,
                                             float* __restrict__ out,
                                             int N) {
    __shared__ __align__(16) float Wt[64 * 64];    // 16 KiB
    __shared__ __align__(16) float xT[64 * 128];   // 32 KiB
    const int tid  = threadIdx.x;
    const int tx   = tid & 15;
    const int ty   = tid >> 4;    // [0,32)
    const int base = blockIdx.x * 128;

    {
        const float4* W4 = (const float4*)W2;
#pragma unroll
        for (int it = 0; it < 2; ++it) {
            int idx = tid + it * 512;              // 1024 total
            int o = idx & 63, k4 = idx >> 6;       // k4 in [0,16)
            float4 v = W4[o * 16 + k4];
            Wt[(4 * k4 + 0) * 64 + o] = v.x;
            Wt[(4 * k4 + 1) * 64 + o] = v.y;
            Wt[(4 * k4 + 2) * 64 + o] = v.z;
            Wt[(4 * k4 + 3) * 64 + o] = v.w;
        }
        const uint2* x2 = (const uint2*)xn;
#pragma unroll
        for (int it = 0; it < 4; ++it) {
            int idx = tid + it * 512;              // 2048 total
            int mm = idx & 127, k4 = idx >> 7;     // k4 in [0,16)
            int node = base + mm;
            U2H v; v.u = make_uint2(0u, 0u);
            float nn = 0.f;
            if (node < N) { v.u = x2[(size_t)node * 16 + k4]; nn = nrm[node]; }
            xT[(4 * k4 + 0) * 128 + mm] = (float)v.h[0].x * nn;
            xT[(4 * k4 + 1) * 128 + mm] = (float)v.h[0].y * nn;
            xT[(4 * k4 + 2) * 128 + mm] = (float)v.h[1].x * nn;
            xT[(4 * k4 + 3) * 128 + mm] = (float)v.h[1].y * nn;
        }
    }
    __syncthreads();

    float4 b4 = ((const float4*)b2)[tx];
    float4 acc[4];
    acc[0] = b4; acc[1] = b4; acc[2] = b4; acc[3] = b4;

#pragma unroll 4
    for (int k = 0; k < 64; ++k) {
        const float4 w4 = *(const float4*)&Wt[k * 64 + 4 * tx];
        const float4 xv = *(const float4*)&xT[k * 128 + 4 * ty];
        acc[0].x = fmaf(xv.x, w4.x, acc[0].x);
        acc[0].y = fmaf(xv.x, w4.y, acc[0].y);
        acc[0].z = fmaf(xv.x, w4.z, acc[0].z);
        acc[0].w = fmaf(xv.x, w4.w, acc[0].w);
        acc[1].x = fmaf(xv.y, w4.x, acc[1].x);
        acc[1].y = fmaf(xv.y, w4.y, acc[1].y);
        acc[1].z = fmaf(xv.y, w4.z, acc[1].z);
        acc[1].w = fmaf(xv.y, w4.w, acc[1].w);
        acc[2].x = fmaf(xv.z, w4.x, acc[2].x);
        acc[2].y = fmaf(xv.z, w4.y, acc[2].y);
        acc[2].z = fmaf(xv.z, w4.z, acc[2].z);
        acc[2].w = fmaf(xv.z, w4.w, acc[2].w);
        acc[3].x = fmaf(xv.w, w4.x, acc[3].x);
        acc[3].y = fmaf(xv.w, w4.y, acc[3].y);
        acc[3].z = fmaf(xv.w, w4.z, acc[3].z);
        acc[3].w = fmaf(xv.w, w4.w, acc[3].w);
    }

#pragma unroll
    for (int mm = 0; mm < 4; ++mm) {
        int node = base + 4 * ty + mm;
        if (node < N) *(float4*)&out[(size_t)node * 64 + 4 * tx] = acc[mm];
    }
}

extern "C" void kernel_launch(void* const* d_in, const int* in_sizes, int n_in,
                              void* d_out, int out_size, void* d_ws, size_t ws_size,
                              hipStream_t stream) {
    const float* x   = (const float*)d_in[0];
    const int*   row = (const int*)d_in[1];
    const int*   col = (const int*)d_in[2];
    const float* W1  = (const float*)d_in[3];
    const float* b1  = (const float*)d_in[4];
    const float* W2  = (const float*)d_in[5];
    const float* b2  = (const float*)d_in[6];
    float* out = (float*)d_out;

    const int N = in_sizes[0] / 128;
    const int E = in_sizes[1];

    char* ws = (char*)d_ws;
    size_t off = 0;
    unsigned short* ha = (unsigned short*)(ws + off); off += (size_t)N * 64 * 2;
    unsigned short* hb = (unsigned short*)(ws + off); off += (size_t)N * 64 * 2;
    float* na_  = (float*)(ws + off); off += (size_t)N * sizeof(float);
    float* nb_  = (float*)(ws + off); off += (size_t)N * sizeof(float);
    int*   ptr  = (int*)  (ws + off); off += (size_t)(N + 1) * sizeof(int);
    off = (off + 15) & ~(size_t)15;
    int*   perm = (int*)  (ws + off); off += (size_t)N * sizeof(int);
    (void)ws_size; (void)n_in; (void)out_size;

    build_rowptr_scan<<<(E + 255) / 256, 256, 0, stream>>>(row, ptr, N, E);

    // segment-local degree sort (all atomics in LDS), 1024-node segments
    build_perm_seg<<<(N + PSEG - 1) / PSEG, 1024, 0, stream>>>(ptr, perm, N);

    const int nbG = (N + 127) / 128;
    gemm1_relu<<<nbG, 512, 0, stream>>>(x, W1, b1, ha, na_, N);

    const int nb16 = (N + 15) / 16;
    unsigned short* hc = ha; unsigned short* hn = hb;
    float* nc = na_; float* nn = nb_;
    for (int l = 0; l < 4; ++l) {
        agnn_layer<<<nb16, 256, 0, stream>>>((const uint4*)hc, nc, ptr, col, perm,
                                             (uint4*)hn, nn, N);
        unsigned short* t = hc; hc = hn; hn = t;
        float* tf = nc; nc = nn; nn = tf;
    }

    gemm2<<<nbG, 512, 0, stream>>>(hc, nc, W2, b2, out, N);
}